// Round 7
// baseline (257.059 us; speedup 1.0000x reference)
//
#include <hip/hip_runtime.h>
#include <hip/hip_fp16.h>
#include <hip/hip_cooperative_groups.h>

namespace cg = cooperative_groups;

#define NBATCH 64
#define NV 50000
#define NT 100000
#define FPB (NV * 3)          /* floats per batch = 150000 */
#define N4 (FPB / 4)          /* 37500 float4 per batch */

#define GRIDB 1024            /* cooperative grid: 4 blocks/CU */
#define WPB 4                 /* waves per block */
#define GWAVES (GRIDB * WPB)  /* 4096 gather waves */
#define NGROUP (NT / 8)       /* 12500 groups of 8 triangles */
#define NTILES ((FPB + 63) / 64)   /* 2344 transpose tiles */
#define CHUNK ((N4 + 15) / 16)     /* 2344 float4 per normalize chunk */

#define XH_HALVES ((size_t)FPB * NBATCH)   /* 9.6e6 halves = 19.2 MB */
#define XH_BYTES (XH_HALVES * 2)
#define WS_NEED (XH_BYTES + (size_t)NBATCH * GWAVES * 8 + 256)

typedef float f32x4 __attribute__((ext_vector_type(4)));
typedef int i32x4 __attribute__((ext_vector_type(4)));

__device__ __forceinline__ float hext(const i32x4& v, int j) {
  const int word = v[j >> 1];
  const __half2 h = __builtin_bit_cast(__half2, word);
  return (j & 1) ? __high2float(h) : __low2float(h);
}

/* ---------------- fused cooperative kernel ----------------
   phase 1: x[b][f] -> fp16 planes xH[c][v][b] (each (c,v) row = one 128B line)
   phase 2: 8-triangle packed gather, per-wave double partials [batch][wave]
   phase 3: per-block deterministic vol reduction (identical fixed-order sum
            in all 16 blocks of a batch) + float4 normalize of its chunk   */
__global__ __launch_bounds__(256) void fused_kernel(
    const float* __restrict__ x, const int* __restrict__ M,
    float* __restrict__ out, __half* __restrict__ xH,
    double* __restrict__ partials) {
  __shared__ float tile[64][65];
  __shared__ double red[4];
  const int tid = threadIdx.x;
  const int tx = tid & 63;   // lane
  const int ty = tid >> 6;   // wave id in block
  cg::grid_group grid = cg::this_grid();

  /* ---- phase 1: transpose ---- */
  for (int t = blockIdx.x; t < NTILES; t += GRIDB) {
    const int f0 = t * 64;
    const int fl = f0 + tx;
    #pragma unroll
    for (int i = ty; i < 64; i += 4)
      if (fl < FPB) tile[i][tx] = x[(size_t)i * FPB + fl];
    __syncthreads();
    #pragma unroll
    for (int i = ty; i < 64; i += 4) {
      const int f = f0 + i;
      if (f < FPB) {
        const int v = f / 3, c = f - 3 * v;
        xH[((size_t)c * NV + v) * 64 + tx] = __float2half(tile[tx][i]);
      }
    }
    __syncthreads();
  }
  grid.sync();

  /* ---- phase 2: packed gather ---- */
  {
    const int w = blockIdx.x * WPB + ty;
    const int sub = tx >> 3;       // triangle slot in group (0..7)
    const int boct = tx & 7;       // batch octet
    const __half* __restrict__ pX = xH;
    const __half* __restrict__ pY = xH + (size_t)NV * 64;
    const __half* __restrict__ pZ = xH + (size_t)2 * NV * 64;
    const size_t o = 8 * boct;     // 16B-aligned offset within 128B row
    double acc[8];
    #pragma unroll
    for (int j = 0; j < 8; ++j) acc[j] = 0.0;

    for (int g = w; g < NGROUP; g += GWAVES) {
      const int t = g * 8 + sub;
      const int i0 = M[3 * t + 0];
      const int i1 = M[3 * t + 1];
      const int i2 = M[3 * t + 2];
      const i32x4 A0 = *(const i32x4*)(pX + (size_t)i0 * 64 + o);
      const i32x4 A1 = *(const i32x4*)(pY + (size_t)i0 * 64 + o);
      const i32x4 A2 = *(const i32x4*)(pZ + (size_t)i0 * 64 + o);
      const i32x4 B0 = *(const i32x4*)(pX + (size_t)i1 * 64 + o);
      const i32x4 B1 = *(const i32x4*)(pY + (size_t)i1 * 64 + o);
      const i32x4 B2 = *(const i32x4*)(pZ + (size_t)i1 * 64 + o);
      const i32x4 C0 = *(const i32x4*)(pX + (size_t)i2 * 64 + o);
      const i32x4 C1 = *(const i32x4*)(pY + (size_t)i2 * 64 + o);
      const i32x4 C2 = *(const i32x4*)(pZ + (size_t)i2 * 64 + o);
      #pragma unroll
      for (int j = 0; j < 8; ++j) {
        const float a0 = hext(A0, j), a1 = hext(A1, j), a2 = hext(A2, j);
        const float b0 = hext(B0, j), b1 = hext(B1, j), b2 = hext(B2, j);
        const float c0 = hext(C0, j), c1 = hext(C1, j), c2 = hext(C2, j);
        const float det = a0 * (b1 * c2 - b2 * c1) +
                          a1 * (b2 * c0 - b0 * c2) +
                          a2 * (b0 * c1 - b1 * c0);
        acc[j] += (double)fabsf(det);
      }
    }
    // reduce over triangle-slot lanes (bits 3..5) — fixed order
    #pragma unroll
    for (int j = 0; j < 8; ++j) {
      acc[j] += __shfl_xor(acc[j], 8, 64);
      acc[j] += __shfl_xor(acc[j], 16, 64);
      acc[j] += __shfl_xor(acc[j], 32, 64);
    }
    if (sub == 0) {
      #pragma unroll
      for (int j = 0; j < 8; ++j)
        partials[(size_t)(boct * 8 + j) * GWAVES + w] = acc[j];
    }
  }
  grid.sync();

  /* ---- phase 3: vol + normalize ---- */
  {
    const int batch = blockIdx.x >> 4;   // 16 blocks per batch
    const int chunk = blockIdx.x & 15;
    const double* __restrict__ pb = partials + (size_t)batch * GWAVES;
    double local = 0.0;
    #pragma unroll
    for (int k = 0; k < GWAVES / 256; ++k) local += pb[tid + k * 256];
    #pragma unroll
    for (int off = 32; off > 0; off >>= 1) local += __shfl_down(local, off, 64);
    if (tx == 0) red[ty] = local;
    __syncthreads();
    // all threads compute identical (fixed-order) vol -> bitwise-same scale
    const double vol = ((red[0] + red[1]) + (red[2] + red[3])) / 6.0;
    const float s = (float)(1.0 / cbrt(vol));
    const f32x4* __restrict__ xb = (const f32x4*)(x + (size_t)batch * FPB);
    f32x4* __restrict__ ob = (f32x4*)(out + (size_t)batch * FPB);
    const int i1 = min((chunk + 1) * CHUNK, N4);
    for (int i = chunk * CHUNK + tid; i < i1; i += 256) {
      f32x4 v = xb[i];
      v *= s;
      __builtin_nontemporal_store(v, &ob[i]);  // out never re-read
    }
  }
}

/* ---------------- fallback: round-6 4-kernel path ---------------- */

__global__ __launch_bounds__(256) void transpose_kernel(
    const float* __restrict__ x, __half* __restrict__ xH) {
  __shared__ float tile[64][65];
  const int tx = threadIdx.x & 63;
  const int ty = threadIdx.x >> 6;
  const int f0 = blockIdx.x * 64;
  const int fl = f0 + tx;
  #pragma unroll
  for (int i = ty; i < 64; i += 4)
    if (fl < FPB) tile[i][tx] = x[(size_t)i * FPB + fl];
  __syncthreads();
  #pragma unroll
  for (int i = ty; i < 64; i += 4) {
    const int f = f0 + i;
    if (f < FPB) {
      const int v = f / 3, c = f - 3 * v;
      xH[((size_t)c * NV + v) * 64 + tx] = __float2half(tile[tx][i]);
    }
  }
}

__global__ __launch_bounds__(256) void gather_det8_kernel(
    const __half* __restrict__ xH, const int* __restrict__ M,
    double* __restrict__ partials) {
  const int w = blockIdx.x * 4 + (threadIdx.x >> 6);
  const int lane = threadIdx.x & 63;
  const int sub = lane >> 3;
  const int boct = lane & 7;
  const __half* __restrict__ pX = xH;
  const __half* __restrict__ pY = xH + (size_t)NV * 64;
  const __half* __restrict__ pZ = xH + (size_t)2 * NV * 64;
  const size_t o = 8 * boct;
  double acc[8];
  #pragma unroll
  for (int j = 0; j < 8; ++j) acc[j] = 0.0;
  for (int g = w; g < NGROUP; g += GWAVES) {
    const int t = g * 8 + sub;
    const int i0 = M[3 * t + 0], i1 = M[3 * t + 1], i2 = M[3 * t + 2];
    const i32x4 A0 = *(const i32x4*)(pX + (size_t)i0 * 64 + o);
    const i32x4 A1 = *(const i32x4*)(pY + (size_t)i0 * 64 + o);
    const i32x4 A2 = *(const i32x4*)(pZ + (size_t)i0 * 64 + o);
    const i32x4 B0 = *(const i32x4*)(pX + (size_t)i1 * 64 + o);
    const i32x4 B1 = *(const i32x4*)(pY + (size_t)i1 * 64 + o);
    const i32x4 B2 = *(const i32x4*)(pZ + (size_t)i1 * 64 + o);
    const i32x4 C0 = *(const i32x4*)(pX + (size_t)i2 * 64 + o);
    const i32x4 C1 = *(const i32x4*)(pY + (size_t)i2 * 64 + o);
    const i32x4 C2 = *(const i32x4*)(pZ + (size_t)i2 * 64 + o);
    #pragma unroll
    for (int j = 0; j < 8; ++j) {
      const float a0 = hext(A0, j), a1 = hext(A1, j), a2 = hext(A2, j);
      const float b0 = hext(B0, j), b1 = hext(B1, j), b2 = hext(B2, j);
      const float c0 = hext(C0, j), c1 = hext(C1, j), c2 = hext(C2, j);
      const float det = a0 * (b1 * c2 - b2 * c1) + a1 * (b2 * c0 - b0 * c2) +
                        a2 * (b0 * c1 - b1 * c0);
      acc[j] += (double)fabsf(det);
    }
  }
  #pragma unroll
  for (int j = 0; j < 8; ++j) {
    acc[j] += __shfl_xor(acc[j], 8, 64);
    acc[j] += __shfl_xor(acc[j], 16, 64);
    acc[j] += __shfl_xor(acc[j], 32, 64);
  }
  if (sub == 0) {
    #pragma unroll
    for (int j = 0; j < 8; ++j)
      partials[(size_t)w * NBATCH + boct * 8 + j] = acc[j];
  }
}

__global__ __launch_bounds__(256) void finalize_t_kernel(
    const double* __restrict__ partials, float* __restrict__ inv_scale) {
  const int b = blockIdx.x;
  double acc = 0.0;
  for (int w = threadIdx.x; w < GWAVES; w += 256)
    acc += partials[(size_t)w * NBATCH + b];
  #pragma unroll
  for (int off = 32; off > 0; off >>= 1) acc += __shfl_down(acc, off, 64);
  __shared__ double lds[4];
  const int lane = threadIdx.x & 63;
  const int wave = threadIdx.x >> 6;
  if (lane == 0) lds[wave] = acc;
  __syncthreads();
  if (threadIdx.x == 0) {
    const double vol = ((lds[0] + lds[1]) + (lds[2] + lds[3])) / 6.0;
    inv_scale[b] = (float)(1.0 / cbrt(vol));
  }
}

__global__ __launch_bounds__(256) void normalize_kernel(
    const float* __restrict__ x, const float* __restrict__ inv_scale,
    float* __restrict__ out) {
  const int b = blockIdx.y;
  const float s = inv_scale[b];
  const f32x4* __restrict__ xin =
      reinterpret_cast<const f32x4*>(x + (size_t)b * FPB);
  f32x4* __restrict__ o = reinterpret_cast<f32x4*>(out + (size_t)b * FPB);
  const int stride = blockDim.x * gridDim.x;
  for (int i = blockIdx.x * blockDim.x + threadIdx.x; i < N4; i += stride) {
    f32x4 v = xin[i];
    v *= s;
    __builtin_nontemporal_store(v, &o[i]);
  }
}

extern "C" void kernel_launch(void* const* d_in, const int* in_sizes, int n_in,
                              void* d_out, int out_size, void* d_ws, size_t ws_size,
                              hipStream_t stream) {
  const float* x = (const float*)d_in[0];
  const int* M = (const int*)d_in[1];
  float* out = (float*)d_out;

  __half* xH = (__half*)d_ws;
  double* partials = (double*)((char*)d_ws + XH_BYTES);

  if (ws_size >= WS_NEED) {
    void* args[] = {(void*)&x, (void*)&M, (void*)&out, (void*)&xH,
                    (void*)&partials};
    hipError_t e = hipLaunchCooperativeKernel(
        (const void*)fused_kernel, dim3(GRIDB), dim3(256), args, 0, stream);
    if (e == hipSuccess) return;
    (void)hipGetLastError();  // clear error, fall through to 4-kernel path
    float* inv_scale = (float*)(partials + (size_t)NBATCH * GWAVES);
    transpose_kernel<<<NTILES, 256, 0, stream>>>(x, xH);
    gather_det8_kernel<<<GWAVES / 4, 256, 0, stream>>>(xH, M, partials);
    finalize_t_kernel<<<NBATCH, 256, 0, stream>>>(partials, inv_scale);
    dim3 gridC(32, NBATCH);
    normalize_kernel<<<gridC, 256, 0, stream>>>(x, inv_scale, out);
  }
}

// Round 8
// 53.798 us; speedup vs baseline: 4.7783x; 4.7783x over previous
//
#include <hip/hip_runtime.h>
#include <hip/hip_fp16.h>

#define NBATCH 64
#define NV 50000
#define NT 100000
#define FPB (NV * 3)          /* floats per batch = 150000 */
#define N4 (FPB / 4)          /* 37500 float4 per batch */

#define NTILES ((FPB + 63) / 64)   /* 2344 transpose tiles */
#define GBLOCKS 2048               /* gather blocks: 8/CU, 32 waves/CU */
#define GWAVES (GBLOCKS * 4)       /* 8192 gather waves, 1-2 groups each */
#define NGROUP (NT / 8)            /* 12500 groups of 8 triangles */
#define NCHUNK 16                  /* normalize blocks per batch */
#define CHUNK ((N4 + NCHUNK - 1) / NCHUNK)   /* 2344 float4 */

#define XH_HALVES ((size_t)FPB * NBATCH)     /* 9.6e6 halves = 19.2 MB */
#define XH_BYTES (XH_HALVES * 2)
#define WS_NEED (XH_BYTES + (size_t)NBATCH * GBLOCKS * 8 + 256)

typedef float f32x4 __attribute__((ext_vector_type(4)));
typedef int i32x4 __attribute__((ext_vector_type(4)));

__device__ __forceinline__ float hext(const i32x4& v, int j) {
  const int word = v[j >> 1];
  const __half2 h = __builtin_bit_cast(__half2, word);
  return (j & 1) ? __high2float(h) : __low2float(h);
}

/* ---- pass 1: x[b][f] -> fp16 planes xH[c][v][b]; (c,v) row = one 128B line */
__global__ __launch_bounds__(256) void transpose_kernel(
    const float* __restrict__ x, __half* __restrict__ xH) {
  __shared__ float tile[64][65];
  const int tx = threadIdx.x & 63;
  const int ty = threadIdx.x >> 6;
  const int f0 = blockIdx.x * 64;
  const int fl = f0 + tx;
  #pragma unroll
  for (int i = ty; i < 64; i += 4)
    if (fl < FPB) tile[i][tx] = x[(size_t)i * FPB + fl];
  __syncthreads();
  #pragma unroll
  for (int i = ty; i < 64; i += 4) {
    const int f = f0 + i;
    if (f < FPB) {
      const int v = f / 3, c = f - 3 * v;
      xH[((size_t)c * NV + v) * 64 + tx] = __float2half(tile[tx][i]);
    }
  }
}

/* ---- pass 2: 8-triangle packed gather; block-reduced partials[b][blk] ----
   lane = (tri_sub = lane>>3, batch_octet = lane&7); one dwordx4 wave-load =
   8 full 128B rows. Per block: 4 waves LDS-reduced -> 64 doubles. */
__global__ __launch_bounds__(256) void gather_det8_kernel(
    const __half* __restrict__ xH, const int* __restrict__ M,
    double* __restrict__ partials) {
  const int ty = threadIdx.x >> 6;
  const int tx = threadIdx.x & 63;
  const int w = blockIdx.x * 4 + ty;
  const int sub = tx >> 3;
  const int boct = tx & 7;
  const __half* __restrict__ pX = xH;
  const __half* __restrict__ pY = xH + (size_t)NV * 64;
  const __half* __restrict__ pZ = xH + (size_t)2 * NV * 64;
  const size_t o = 8 * boct;
  __shared__ double red[4][64];

  double acc[8];
  #pragma unroll
  for (int j = 0; j < 8; ++j) acc[j] = 0.0;

  for (int g = w; g < NGROUP; g += GWAVES) {   /* 1 or 2 iterations */
    const int t = g * 8 + sub;
    const int i0 = M[3 * t + 0];
    const int i1 = M[3 * t + 1];
    const int i2 = M[3 * t + 2];
    const i32x4 A0 = *(const i32x4*)(pX + (size_t)i0 * 64 + o);
    const i32x4 A1 = *(const i32x4*)(pY + (size_t)i0 * 64 + o);
    const i32x4 A2 = *(const i32x4*)(pZ + (size_t)i0 * 64 + o);
    const i32x4 B0 = *(const i32x4*)(pX + (size_t)i1 * 64 + o);
    const i32x4 B1 = *(const i32x4*)(pY + (size_t)i1 * 64 + o);
    const i32x4 B2 = *(const i32x4*)(pZ + (size_t)i1 * 64 + o);
    const i32x4 C0 = *(const i32x4*)(pX + (size_t)i2 * 64 + o);
    const i32x4 C1 = *(const i32x4*)(pY + (size_t)i2 * 64 + o);
    const i32x4 C2 = *(const i32x4*)(pZ + (size_t)i2 * 64 + o);
    #pragma unroll
    for (int j = 0; j < 8; ++j) {
      const float a0 = hext(A0, j), a1 = hext(A1, j), a2 = hext(A2, j);
      const float b0 = hext(B0, j), b1 = hext(B1, j), b2 = hext(B2, j);
      const float c0 = hext(C0, j), c1 = hext(C1, j), c2 = hext(C2, j);
      const float det = a0 * (b1 * c2 - b2 * c1) +
                        a1 * (b2 * c0 - b0 * c2) +
                        a2 * (b0 * c1 - b1 * c0);
      acc[j] += (double)fabsf(det);
    }
  }
  /* reduce over tri-sub lanes (bits 3..5) — fixed order, deterministic */
  #pragma unroll
  for (int j = 0; j < 8; ++j) {
    acc[j] += __shfl_xor(acc[j], 8, 64);
    acc[j] += __shfl_xor(acc[j], 16, 64);
    acc[j] += __shfl_xor(acc[j], 32, 64);
  }
  if (sub == 0) {
    #pragma unroll
    for (int j = 0; j < 8; ++j) red[ty][boct * 8 + j] = acc[j];
  }
  __syncthreads();
  /* wave 0: cross-wave sum (fixed order), partials[b][blk] for contig read */
  if (ty == 0) {
    const double s = ((red[0][tx] + red[1][tx]) + (red[2][tx] + red[3][tx]));
    partials[(size_t)tx * GBLOCKS + blockIdx.x] = s;
  }
}

/* ---- pass 3: fused finalize + normalize ----
   Each of the 16 blocks per batch redundantly sums that batch's 2048 block
   partials in IDENTICAL fixed order -> bitwise-same scale; then scales its
   float4 chunk. */
__global__ __launch_bounds__(256) void normfin_kernel(
    const float* __restrict__ x, const double* __restrict__ partials,
    float* __restrict__ out) {
  const int batch = blockIdx.x >> 4;
  const int chunk = blockIdx.x & (NCHUNK - 1);
  const int tid = threadIdx.x;
  const int tx = tid & 63;
  const int ty = tid >> 6;
  __shared__ double red[4];

  const double* __restrict__ pb = partials + (size_t)batch * GBLOCKS;
  double local = 0.0;
  #pragma unroll
  for (int k = 0; k < GBLOCKS / 256; ++k) local += pb[tid + k * 256];
  #pragma unroll
  for (int off = 32; off > 0; off >>= 1) local += __shfl_down(local, off, 64);
  if (tx == 0) red[ty] = local;
  __syncthreads();
  const double vol = ((red[0] + red[1]) + (red[2] + red[3])) / 6.0;
  const float s = (float)(1.0 / cbrt(vol));

  const f32x4* __restrict__ xb = (const f32x4*)(x + (size_t)batch * FPB);
  f32x4* __restrict__ ob = (f32x4*)(out + (size_t)batch * FPB);
  const int i1 = min((chunk + 1) * CHUNK, N4);
  for (int i = chunk * CHUNK + tid; i < i1; i += 256) {
    f32x4 v = xb[i];
    v *= s;
    __builtin_nontemporal_store(v, &ob[i]);  /* out never re-read */
  }
}

/* ---------------- fallback (small ws): round-2 XCD-local path ------------ */

#define XCDS 8
#define SLOTS 256
#define BATCH_PER_XCD (NBATCH / XCDS)

__global__ __launch_bounds__(256) void vol_partial_kernel(
    const float* __restrict__ x, const int* __restrict__ M,
    double* __restrict__ partials) {
  const int L = blockIdx.x;
  const int xcd = L & (XCDS - 1);
  const int slot = L >> 3;
  __shared__ double lds[4];
  const int lane = threadIdx.x & 63;
  const int wave = threadIdx.x >> 6;
  for (int bi = 0; bi < BATCH_PER_XCD; ++bi) {
    const int b = xcd * BATCH_PER_XCD + bi;
    const float* __restrict__ xv = x + (size_t)b * FPB;
    double acc = 0.0;
    for (int t = slot * 256 + threadIdx.x; t < NT; t += SLOTS * 256) {
      const int i0 = M[3 * t + 0], i1 = M[3 * t + 1], i2 = M[3 * t + 2];
      const float a0 = xv[3 * i0], a1 = xv[3 * i0 + 1], a2 = xv[3 * i0 + 2];
      const float b0 = xv[3 * i1], b1 = xv[3 * i1 + 1], b2 = xv[3 * i1 + 2];
      const float c0 = xv[3 * i2], c1 = xv[3 * i2 + 1], c2 = xv[3 * i2 + 2];
      const float det = a0 * (b1 * c2 - b2 * c1) + a1 * (b2 * c0 - b0 * c2) +
                        a2 * (b0 * c1 - b1 * c0);
      acc += (double)fabsf(det);
    }
    #pragma unroll
    for (int off = 32; off > 0; off >>= 1) acc += __shfl_down(acc, off, 64);
    if (lane == 0) lds[wave] = acc;
    __syncthreads();
    if (threadIdx.x == 0)
      partials[(size_t)b * SLOTS + slot] = (lds[0] + lds[1]) + (lds[2] + lds[3]);
    __syncthreads();
  }
}

__global__ __launch_bounds__(256) void finalize_kernel(
    const double* __restrict__ partials, float* __restrict__ inv_scale) {
  const int b = blockIdx.x;
  double v = partials[(size_t)b * SLOTS + threadIdx.x];
  #pragma unroll
  for (int off = 32; off > 0; off >>= 1) v += __shfl_down(v, off, 64);
  __shared__ double lds[4];
  const int lane = threadIdx.x & 63;
  const int wave = threadIdx.x >> 6;
  if (lane == 0) lds[wave] = v;
  __syncthreads();
  if (threadIdx.x == 0) {
    const double vol = ((lds[0] + lds[1]) + (lds[2] + lds[3])) / 6.0;
    inv_scale[b] = (float)(1.0 / cbrt(vol));
  }
}

__global__ __launch_bounds__(256) void normalize_kernel(
    const float* __restrict__ x, const float* __restrict__ inv_scale,
    float* __restrict__ out) {
  const int b = blockIdx.y;
  const float s = inv_scale[b];
  const f32x4* __restrict__ xin =
      reinterpret_cast<const f32x4*>(x + (size_t)b * FPB);
  f32x4* __restrict__ o = reinterpret_cast<f32x4*>(out + (size_t)b * FPB);
  const int stride = blockDim.x * gridDim.x;
  for (int i = blockIdx.x * blockDim.x + threadIdx.x; i < N4; i += stride) {
    f32x4 v = xin[i];
    v *= s;
    __builtin_nontemporal_store(v, &o[i]);
  }
}

extern "C" void kernel_launch(void* const* d_in, const int* in_sizes, int n_in,
                              void* d_out, int out_size, void* d_ws, size_t ws_size,
                              hipStream_t stream) {
  const float* x = (const float*)d_in[0];
  const int* M = (const int*)d_in[1];
  float* out = (float*)d_out;

  if (ws_size >= WS_NEED) {
    __half* xH = (__half*)d_ws;
    double* partials = (double*)((char*)d_ws + XH_BYTES);
    transpose_kernel<<<NTILES, 256, 0, stream>>>(x, xH);
    gather_det8_kernel<<<GBLOCKS, 256, 0, stream>>>(xH, M, partials);
    normfin_kernel<<<NBATCH * NCHUNK, 256, 0, stream>>>(x, partials, out);
  } else {
    double* partials = (double*)d_ws;
    float* inv_scale = (float*)(partials + NBATCH * SLOTS);
    vol_partial_kernel<<<XCDS * SLOTS, 256, 0, stream>>>(x, M, partials);
    finalize_kernel<<<NBATCH, SLOTS, 0, stream>>>(partials, inv_scale);
    dim3 gridC(32, NBATCH);
    normalize_kernel<<<gridC, 256, 0, stream>>>(x, inv_scale, out);
  }
}